// Round 1
// baseline (4986.241 us; speedup 1.0000x reference)
//
#include <hip/hip_runtime.h>
#include <hip/hip_bf16.h>

#define T_SEQ 4096
#define NH    16
#define DQK   192
#define DR    64
#define DV    128
#define RK    512
#define ATT_SCALE 0.07216878364870323f   // 192^-0.5
#define LOG2_10000 13.287712379549449f

// ---------------- generic NT GEMM: C[M,N] = A[M,K] * Bt[N,K]^T ----------------
// 128x128 tile, BK=8, 256 threads, 8x8 per thread. Wave remapped to 8x8 (tx,ty)
// footprint so LDS b128 reads are 2-way (conflict-free per m136).
__global__ __launch_bounds__(256) void gemm_nt(const float* __restrict__ A,
                                               const float* __restrict__ Bt,
                                               float* __restrict__ C,
                                               int M, int N, int K) {
  __shared__ float As[8][128];
  __shared__ float Bs[8][128];
  const int tid  = threadIdx.x;
  const int w    = tid >> 6;
  const int lane = tid & 63;
  const int tx = (lane & 7) + ((w & 1) << 3);          // 0..15
  const int ty = ((lane >> 3) & 7) + ((w >> 1) << 3);  // 0..15
  const int bm = blockIdx.y * 128;
  const int bn = blockIdx.x * 128;
  const int lr = tid >> 1;          // 0..127
  const int lk = (tid & 1) << 2;    // 0 or 4

  float acc[8][8];
#pragma unroll
  for (int i = 0; i < 8; ++i)
#pragma unroll
    for (int j = 0; j < 8; ++j) acc[i][j] = 0.f;

  const float* Aptr = A + (size_t)(bm + lr) * K + lk;
  const float* Bptr = Bt + (size_t)(bn + lr) * K + lk;
  const bool bok = (bn + lr) < N;

  for (int k0 = 0; k0 < K; k0 += 8) {
    float4 av = *(const float4*)(Aptr + k0);
    float4 bv = bok ? *(const float4*)(Bptr + k0) : make_float4(0.f, 0.f, 0.f, 0.f);
    __syncthreads();
    As[lk + 0][lr] = av.x; As[lk + 1][lr] = av.y; As[lk + 2][lr] = av.z; As[lk + 3][lr] = av.w;
    Bs[lk + 0][lr] = bv.x; Bs[lk + 1][lr] = bv.y; Bs[lk + 2][lr] = bv.z; Bs[lk + 3][lr] = bv.w;
    __syncthreads();
#pragma unroll
    for (int kk = 0; kk < 8; ++kk) {
      float a[8], b[8];
      *(float4*)&a[0] = *(const float4*)&As[kk][ty * 8];
      *(float4*)&a[4] = *(const float4*)&As[kk][ty * 8 + 4];
      *(float4*)&b[0] = *(const float4*)&Bs[kk][tx * 8];
      *(float4*)&b[4] = *(const float4*)&Bs[kk][tx * 8 + 4];
#pragma unroll
      for (int i = 0; i < 8; ++i)
#pragma unroll
        for (int j = 0; j < 8; ++j)
          acc[i][j] = fmaf(a[i], b[j], acc[i][j]);
    }
  }
#pragma unroll
  for (int i = 0; i < 8; ++i) {
    const size_t row = (size_t)(bm + ty * 8 + i) * (size_t)N;
#pragma unroll
    for (int j = 0; j < 8; ++j) {
      int n = bn + tx * 8 + j;
      if (n < N) C[row + n] = acc[i][j];
    }
  }
}

// ---------------- RoPE on q_pe (in place) ----------------
__global__ __launch_bounds__(256) void rope_q(float* __restrict__ q) {
  int idx = blockIdx.x * 256 + threadIdx.x;   // T*H*32
  int i = idx & 31;
  int th = idx >> 5;
  int h = th & 15;
  int t = th >> 4;
  float fr = exp2f(-(float)i * (LOG2_10000 / 32.f));
  float ang = (float)t * fr;
  float sn, cs;
  sincosf(ang, &sn, &cs);
  float* p = q + (size_t)t * 3072 + h * 192 + 128 + 2 * i;
  float a = p[0], b = p[1];
  p[0] = a * cs - b * sn;
  p[1] = a * sn + b * cs;
}

// ---------------- LayerNorm(kv) + RoPE(k_pe) ----------------
__global__ __launch_bounds__(256) void ln_rope_k(const float* __restrict__ kvfull,
                                                 const float* __restrict__ gamma,
                                                 const float* __restrict__ beta,
                                                 float* __restrict__ kvln,
                                                 float* __restrict__ kpe) {
  const int t = blockIdx.x;
  const int tid = threadIdx.x;
  const float* row = kvfull + (size_t)t * 576;
  float x0 = row[tid], x1 = row[tid + 256];
  float sm = x0 + x1;
  float sq = x0 * x0 + x1 * x1;
#pragma unroll
  for (int off = 1; off < 64; off <<= 1) {
    sm += __shfl_xor(sm, off, 64);
    sq += __shfl_xor(sq, off, 64);
  }
  __shared__ float rs[4], rq[4];
  const int lane = tid & 63, wid = tid >> 6;
  if (lane == 0) { rs[wid] = sm; rq[wid] = sq; }
  __syncthreads();
  float tsm = rs[0] + rs[1] + rs[2] + rs[3];
  float tsq = rq[0] + rq[1] + rq[2] + rq[3];
  float mu = tsm * (1.f / 512.f);
  float var = tsq * (1.f / 512.f) - mu * mu;
  float inv = rsqrtf(var + 1e-5f);
  kvln[(size_t)t * 512 + tid]       = (x0 - mu) * inv * gamma[tid] + beta[tid];
  kvln[(size_t)t * 512 + tid + 256] = (x1 - mu) * inv * gamma[tid + 256] + beta[tid + 256];
  if (tid < 32) {
    float a = row[512 + 2 * tid], b = row[512 + 2 * tid + 1];
    float fr = exp2f(-(float)tid * (LOG2_10000 / 32.f));
    float ang = (float)t * fr;
    float sn, cs;
    sincosf(ang, &sn, &cs);
    kpe[(size_t)t * 64 + 2 * tid]     = a * cs - b * sn;
    kpe[(size_t)t * 64 + 2 * tid + 1] = a * sn + b * cs;
  }
}

// ---------------- flash attention, causal, 128x128 tiles ----------------
// q:   [T][H][192]  (pe part already roped)
// kvb: [T][H][256]  (c<128: k_nope, c>=128: v)
// kpe: [T][64]
// aout:[T][H*128]
__global__ __launch_bounds__(256) void attn_kernel(const float* __restrict__ q,
                                                   const float* __restrict__ kvb,
                                                   const float* __restrict__ kpe,
                                                   float* __restrict__ aout) {
  __shared__ __hip_bfloat16 sQK[16384];      // Qch[64][128] @0, Kch[64][128] @8192; Ps[128][128] aliases all
  __shared__ __hip_bfloat16 sV[128][128];
  const int h = blockIdx.y;
  const int bx = blockIdx.x;
  const int qt = (bx & 1) ? (31 - (bx >> 1)) : (bx >> 1);  // pair long+short for balance
  const int tid = threadIdx.x;
  const int tx = tid & 15;
  const int ty = tid >> 4;
  const int q0 = qt * 128;

  float o[8][8];
  float mi[8], li[8];
#pragma unroll
  for (int i = 0; i < 8; ++i) {
    mi[i] = -1e30f; li[i] = 0.f;
#pragma unroll
    for (int j = 0; j < 8; ++j) o[i][j] = 0.f;
  }

  for (int kt = 0; kt <= qt; ++kt) {
    const int k0 = kt * 128;
    __syncthreads();   // prev iteration's PV reads of sV/Ps done
    // stage V tile (bf16)
    {
      const int c4 = (tid & 31) * 4;
      const int r0 = tid >> 5;
#pragma unroll
      for (int r = 0; r < 16; ++r) {
        int row = r * 8 + r0;
        float4 v4 = *(const float4*)(kvb + (size_t)(k0 + row) * 4096 + h * 256 + 128 + c4);
        sV[row][c4 + 0] = __float2bfloat16(v4.x);
        sV[row][c4 + 1] = __float2bfloat16(v4.y);
        sV[row][c4 + 2] = __float2bfloat16(v4.z);
        sV[row][c4 + 3] = __float2bfloat16(v4.w);
      }
    }
    float s[8][8];
#pragma unroll
    for (int i = 0; i < 8; ++i)
#pragma unroll
      for (int j = 0; j < 8; ++j) s[i][j] = 0.f;

    // S = Q K^T over 3 chunks of 64 c (0..191; c>=128 comes from kpe)
    for (int ch = 0; ch < 3; ++ch) {
      const int c0 = ch * 64;
      __syncthreads();  // previous chunk's compute reads done before overwrite
      {
        const int cc4 = tx * 4;
        const int c = c0 + cc4;
#pragma unroll
        for (int r = 0; r < 8; ++r) {
          int m = r * 16 + ty;
          float4 a4 = *(const float4*)(q + (size_t)(q0 + m) * 3072 + h * 192 + c0 + cc4);
          sQK[(cc4 + 0) * 128 + m] = __float2bfloat16(a4.x);
          sQK[(cc4 + 1) * 128 + m] = __float2bfloat16(a4.y);
          sQK[(cc4 + 2) * 128 + m] = __float2bfloat16(a4.z);
          sQK[(cc4 + 3) * 128 + m] = __float2bfloat16(a4.w);
          float4 b4;
          if (c < 128)
            b4 = *(const float4*)(kvb + (size_t)(k0 + m) * 4096 + h * 256 + c);
          else
            b4 = *(const float4*)(kpe + (size_t)(k0 + m) * 64 + (c - 128));
          sQK[8192 + (cc4 + 0) * 128 + m] = __float2bfloat16(b4.x);
          sQK[8192 + (cc4 + 1) * 128 + m] = __float2bfloat16(b4.y);
          sQK[8192 + (cc4 + 2) * 128 + m] = __float2bfloat16(b4.z);
          sQK[8192 + (cc4 + 3) * 128 + m] = __float2bfloat16(b4.w);
        }
      }
      __syncthreads();
#pragma unroll 4
      for (int cc = 0; cc < 64; ++cc) {
        float4 araw = *(const float4*)&sQK[cc * 128 + ty * 8];
        float4 braw = *(const float4*)&sQK[8192 + cc * 128 + tx * 8];
        const __hip_bfloat16* ah = (const __hip_bfloat16*)&araw;
        const __hip_bfloat16* bh = (const __hip_bfloat16*)&braw;
        float af[8], bf[8];
#pragma unroll
        for (int e = 0; e < 8; ++e) {
          af[e] = __bfloat162float(ah[e]);
          bf[e] = __bfloat162float(bh[e]);
        }
#pragma unroll
        for (int i = 0; i < 8; ++i)
#pragma unroll
          for (int j = 0; j < 8; ++j)
            s[i][j] = fmaf(af[i], bf[j], s[i][j]);
      }
    }

    // online softmax (rows owned by 16 consecutive lanes; shfl-xor over low 4 bits)
    const bool diag = (kt == qt);
#pragma unroll
    for (int i = 0; i < 8; ++i) {
      const int gm = q0 + ty * 8 + i;
      float rmax = -1e30f;
#pragma unroll
      for (int j = 0; j < 8; ++j) {
        float v = s[i][j] * ATT_SCALE;
        if (diag && (k0 + tx * 8 + j) > gm) v = -1e30f;
        s[i][j] = v;
        rmax = fmaxf(rmax, v);
      }
      rmax = fmaxf(rmax, __shfl_xor(rmax, 1, 64));
      rmax = fmaxf(rmax, __shfl_xor(rmax, 2, 64));
      rmax = fmaxf(rmax, __shfl_xor(rmax, 4, 64));
      rmax = fmaxf(rmax, __shfl_xor(rmax, 8, 64));
      const float mnew = fmaxf(mi[i], rmax);
      const float alpha = __expf(mi[i] - mnew);
      float rsum = 0.f;
#pragma unroll
      for (int j = 0; j < 8; ++j) {
        float p = __expf(s[i][j] - mnew);
        s[i][j] = p;
        rsum += p;
      }
      rsum += __shfl_xor(rsum, 1, 64);
      rsum += __shfl_xor(rsum, 2, 64);
      rsum += __shfl_xor(rsum, 4, 64);
      rsum += __shfl_xor(rsum, 8, 64);
      li[i] = li[i] * alpha + rsum;
      mi[i] = mnew;
#pragma unroll
      for (int j = 0; j < 8; ++j) o[i][j] *= alpha;
    }
    __syncthreads();  // all S reads of sQK done
    // write P (n-major) into sQK alias
#pragma unroll
    for (int i = 0; i < 8; ++i)
#pragma unroll
      for (int j = 0; j < 8; ++j)
        sQK[(tx * 8 + j) * 128 + ty * 8 + i] = __float2bfloat16(s[i][j]);
    __syncthreads();
    // O += P V
#pragma unroll 2
    for (int n = 0; n < 128; ++n) {
      float4 praw = *(const float4*)&sQK[n * 128 + ty * 8];
      float4 vraw = *(const float4*)&sV[n][tx * 8];
      const __hip_bfloat16* ph = (const __hip_bfloat16*)&praw;
      const __hip_bfloat16* vh = (const __hip_bfloat16*)&vraw;
      float pf[8], vf[8];
#pragma unroll
      for (int e = 0; e < 8; ++e) {
        pf[e] = __bfloat162float(ph[e]);
        vf[e] = __bfloat162float(vh[e]);
      }
#pragma unroll
      for (int i = 0; i < 8; ++i)
#pragma unroll
        for (int j = 0; j < 8; ++j)
          o[i][j] = fmaf(pf[i], vf[j], o[i][j]);
    }
  }

#pragma unroll
  for (int i = 0; i < 8; ++i) {
    const float inv = 1.f / li[i];
    const int gm = q0 + ty * 8 + i;
    float4 o0, o1;
    o0.x = o[i][0] * inv; o0.y = o[i][1] * inv; o0.z = o[i][2] * inv; o0.w = o[i][3] * inv;
    o1.x = o[i][4] * inv; o1.y = o[i][5] * inv; o1.z = o[i][6] * inv; o1.w = o[i][7] * inv;
    float* dst = aout + (size_t)gm * 2048 + h * 128 + tx * 8;
    *(float4*)dst = o0;
    *(float4*)(dst + 4) = o1;
  }
}

extern "C" void kernel_launch(void* const* d_in, const int* in_sizes, int n_in,
                              void* d_out, int out_size, void* d_ws, size_t ws_size,
                              hipStream_t stream) {
  const float* x        = (const float*)d_in[0];
  const float* wq       = (const float*)d_in[1];
  const float* wkv_a    = (const float*)d_in[2];
  const float* kv_gamma = (const float*)d_in[3];
  const float* kv_beta  = (const float*)d_in[4];
  const float* wkv_b    = (const float*)d_in[5];
  const float* wo       = (const float*)d_in[6];
  float* out = (float*)d_out;

  float* ws = (float*)d_ws;
  size_t off = 0;
  float* qb     = ws + off; off += (size_t)T_SEQ * NH * DQK;   // roped q
  float* kvfull = ws + off; off += (size_t)T_SEQ * 576;
  float* kvln   = ws + off; off += (size_t)T_SEQ * RK;
  float* kpeb   = ws + off; off += (size_t)T_SEQ * DR;
  float* kvbb   = ws + off; off += (size_t)T_SEQ * NH * 256;   // [k_nope | v]
  float* attnb  = ws + off; off += (size_t)T_SEQ * NH * DV;
  if (ws_size < off * sizeof(float)) return;  // workspace too small — fail loudly (zero out)

  // 1. q = x @ wq^T  (4096 x 3072 x 2048)
  gemm_nt<<<dim3(24, 32), 256, 0, stream>>>(x, wq, qb, 4096, 3072, 2048);
  // 2. rope(q_pe) in place
  rope_q<<<dim3(8192), 256, 0, stream>>>(qb);
  // 3. kv_full = x @ wkv_a^T  (4096 x 576 x 2048)
  gemm_nt<<<dim3(5, 32), 256, 0, stream>>>(x, wkv_a, kvfull, 4096, 576, 2048);
  // 4. layernorm + rope(k_pe)
  ln_rope_k<<<dim3(4096), 256, 0, stream>>>(kvfull, kv_gamma, kv_beta, kvln, kpeb);
  // 5. kvb = kvln @ wkv_b^T  (4096 x 4096 x 512)
  gemm_nt<<<dim3(32, 32), 256, 0, stream>>>(kvln, wkv_b, kvbb, 4096, 4096, 512);
  // 6. causal flash attention
  attn_kernel<<<dim3(32, 16), 256, 0, stream>>>(qb, kvbb, kpeb, attnb);
  // 7. out = attn @ wo^T  (4096 x 2048 x 2048)
  gemm_nt<<<dim3(16, 32), 256, 0, stream>>>(attnb, wo, out, 4096, 2048, 2048);
}

// Round 2
// 701.451 us; speedup vs baseline: 7.1085x; 7.1085x over previous
//
#include <hip/hip_runtime.h>
#include <hip/hip_bf16.h>

typedef __attribute__((ext_vector_type(8))) short bf16x8;
typedef __attribute__((ext_vector_type(4))) float f32x4;
typedef __attribute__((address_space(3))) unsigned int lds_u32;
typedef __attribute__((address_space(1))) const unsigned int glb_u32;

#define LOG2_10000 13.287712379549449f
#define ATT_SCALE 0.07216878364870323f

static __device__ __forceinline__ unsigned short f2bf(float f) {
  union { float f; unsigned int u; } v; v.f = f;
  unsigned int r = v.u + 0x7FFFu + ((v.u >> 16) & 1u);
  return (unsigned short)(r >> 16);
}
static __device__ __forceinline__ float bf2f(unsigned short h) {
  union { unsigned int u; float f; } v; v.u = ((unsigned int)h) << 16;
  return v.f;
}
static __device__ __forceinline__ f32x4 mfma16(bf16x8 a, bf16x8 b, f32x4 c) {
  return __builtin_amdgcn_mfma_f32_16x16x32_bf16(a, b, c, 0, 0, 0);
}
static __device__ __forceinline__ void gl_lds16(const void* g, void* l) {
  __builtin_amdgcn_global_load_lds((glb_u32*)g, (lds_u32*)l, 16, 0, 0);
}

// ---------- cast f32 -> bf16 with trailing zero-fill (pad region) ----------
__global__ __launch_bounds__(256) void cast_bf16(const float* __restrict__ src,
                                                 unsigned short* __restrict__ dst,
                                                 int nsrc, int ndst) {
  int i = (blockIdx.x * 256 + threadIdx.x) * 4;
  if (i >= ndst) return;
  float4 v = make_float4(0.f, 0.f, 0.f, 0.f);
  if (i < nsrc) v = *(const float4*)(src + i);   // nsrc is a multiple of 4
  uint2 o;
  o.x = (unsigned int)f2bf(v.x) | ((unsigned int)f2bf(v.y) << 16);
  o.y = (unsigned int)f2bf(v.z) | ((unsigned int)f2bf(v.w) << 16);
  *(uint2*)(dst + i) = o;
}

// ---------- bf16 NT GEMM: C[M,N] = A[M,K] * Bt[N,K]^T  (m97 structure) ----------
// 128x128 tile, BK=32, 256 thr / 4 waves, wave = 64x64 via 4x4 of 16x16x32 MFMA.
template <bool OUTBF>
__global__ __launch_bounds__(256, 2) void gemm_bf16(const unsigned short* __restrict__ A,
                                                    const unsigned short* __restrict__ Bt,
                                                    void* __restrict__ Cv,
                                                    int M, int N, int K) {
  __shared__ unsigned short As[128 * 32];
  __shared__ unsigned short Bs[128 * 32];
  const int tid = threadIdx.x;
  const int w = tid >> 6, lane = tid & 63;
  const int quad = lane >> 4, l15 = lane & 15;
  const int wx = w & 1, wy = w >> 1;
  const int bm = blockIdx.y * 128, bn = blockIdx.x * 128;

  f32x4 acc[4][4];
#pragma unroll
  for (int i = 0; i < 4; ++i)
#pragma unroll
    for (int j = 0; j < 4; ++j) { acc[i][j][0] = 0.f; acc[i][j][1] = 0.f; acc[i][j][2] = 0.f; acc[i][j][3] = 0.f; }

  const int lrow = lane >> 2;        // 0..15
  const int lcol = (lane & 3) * 8;   // elem offset within BK
  const unsigned short* Ag = A + (size_t)(bm + w * 16 + lrow) * K + lcol;
  const unsigned short* Bg = Bt + (size_t)(bn + w * 16 + lrow) * K + lcol;
  unsigned short* AsB = &As[(w * 16) * 32];
  unsigned short* BsB = &Bs[(w * 16) * 32];

  for (int k0 = 0; k0 < K; k0 += 32) {
    __syncthreads();
    gl_lds16(Ag + k0, AsB);
    gl_lds16(Ag + (size_t)64 * K + k0, AsB + 64 * 32);
    gl_lds16(Bg + k0, BsB);
    gl_lds16(Bg + (size_t)64 * K + k0, BsB + 64 * 32);
    __syncthreads();
    bf16x8 aF[4], bF[4];
#pragma unroll
    for (int i = 0; i < 4; ++i)
      aF[i] = *(const bf16x8*)&As[(wy * 64 + i * 16 + l15) * 32 + quad * 8];
#pragma unroll
    for (int j = 0; j < 4; ++j)
      bF[j] = *(const bf16x8*)&Bs[(wx * 64 + j * 16 + l15) * 32 + quad * 8];
#pragma unroll
    for (int i = 0; i < 4; ++i)
#pragma unroll
      for (int j = 0; j < 4; ++j)
        acc[i][j] = mfma16(aF[i], bF[j], acc[i][j]);
  }

#pragma unroll
  for (int i = 0; i < 4; ++i)
#pragma unroll
    for (int r = 0; r < 4; ++r) {
      const size_t row = (size_t)(bm + wy * 64 + i * 16 + quad * 4 + r) * (size_t)N;
#pragma unroll
      for (int j = 0; j < 4; ++j) {
        const int col = bn + wx * 64 + j * 16 + l15;
        if (OUTBF) ((unsigned short*)Cv)[row + col] = f2bf(acc[i][j][r]);
        else       ((float*)Cv)[row + col] = acc[i][j][r];
      }
    }
}

// ---------- RoPE on q_pe, in place on bf16 q ----------
__global__ __launch_bounds__(256) void rope_q_bf(unsigned short* __restrict__ qh) {
  int idx = blockIdx.x * 256 + threadIdx.x;  // T*H*32
  int j = idx & 31;
  int th = idx >> 5;
  int h = th & 15;
  int t = th >> 4;
  float fr = exp2f(-(float)j * (LOG2_10000 / 32.f));
  float ang = (float)t * fr;
  float sn, cs;
  sincosf(ang, &sn, &cs);
  unsigned short* p = qh + (size_t)t * 3072 + h * 192 + 128 + 2 * j;
  unsigned int v = *(unsigned int*)p;
  float a = bf2f((unsigned short)v), b = bf2f((unsigned short)(v >> 16));
  float na = a * cs - b * sn, nb = a * sn + b * cs;
  *(unsigned int*)p = (unsigned int)f2bf(na) | ((unsigned int)f2bf(nb) << 16);
}

// ---------- LayerNorm(kv) + RoPE(k_pe); f32 in (stride 640), bf16 out ----------
__global__ __launch_bounds__(256) void ln_rope_k(const float* __restrict__ kvfull,
                                                 const float* __restrict__ gamma,
                                                 const float* __restrict__ beta,
                                                 unsigned short* __restrict__ kvln,
                                                 unsigned short* __restrict__ kpe) {
  const int t = blockIdx.x;
  const int tid = threadIdx.x;
  const float* row = kvfull + (size_t)t * 640;
  float x0 = row[tid], x1 = row[tid + 256];
  float sm = x0 + x1;
  float sq = x0 * x0 + x1 * x1;
#pragma unroll
  for (int off = 1; off < 64; off <<= 1) {
    sm += __shfl_xor(sm, off, 64);
    sq += __shfl_xor(sq, off, 64);
  }
  __shared__ float rs[4], rq[4];
  const int lane = tid & 63, wid = tid >> 6;
  if (lane == 0) { rs[wid] = sm; rq[wid] = sq; }
  __syncthreads();
  float tsm = rs[0] + rs[1] + rs[2] + rs[3];
  float tsq = rq[0] + rq[1] + rq[2] + rq[3];
  float mu = tsm * (1.f / 512.f);
  float var = tsq * (1.f / 512.f) - mu * mu;
  float inv = rsqrtf(var + 1e-5f);
  kvln[(size_t)t * 512 + tid]       = f2bf((x0 - mu) * inv * gamma[tid] + beta[tid]);
  kvln[(size_t)t * 512 + tid + 256] = f2bf((x1 - mu) * inv * gamma[tid + 256] + beta[tid + 256]);
  if (tid < 32) {
    float a = row[512 + 2 * tid], b = row[512 + 2 * tid + 1];
    float fr = exp2f(-(float)tid * (LOG2_10000 / 32.f));
    float ang = (float)t * fr;
    float sn, cs;
    sincosf(ang, &sn, &cs);
    kpe[(size_t)t * 64 + 2 * tid]     = f2bf(a * cs - b * sn);
    kpe[(size_t)t * 64 + 2 * tid + 1] = f2bf(a * sn + b * cs);
  }
}

// ---------- MFMA flash attention, causal ----------
// qh:[T][3072] bf16 (roped), kvb:[T][4096] bf16 (h*256 + [k_nope|v]), kpe:[T][64] bf16
// out attnh:[T][2048] bf16.  Block = 256 thr / 4 waves, Q-tile 128 (wave = 32 rows),
// K-steps of 64 keys.  LDS: sK[64][200] (2-way banks), sVt[128][72] (V^T), sP aliases sK.
__global__ __launch_bounds__(256, 2) void attn_mfma(const unsigned short* __restrict__ qh,
                                                    const unsigned short* __restrict__ kvb,
                                                    const unsigned short* __restrict__ kpe,
                                                    unsigned short* __restrict__ attnh) {
  __shared__ unsigned short sK[64 * 200];    // >= 128*72 for sP alias
  __shared__ unsigned short sVt[128 * 72];
  unsigned short* sP = sK;

  const int bid = blockIdx.x;
  const int h = bid & 15;
  const int z = bid >> 4;                  // 0..31
  const int qt = (z < 16) ? z : 47 - z;    // pair (z, z+16) -> (qt, 31-qt): balanced per CU
  const int q0 = qt * 128;
  const int tid = threadIdx.x;
  const int w = tid >> 6, lane = tid & 63;
  const int quad = lane >> 4, l15 = lane & 15;
  const int wq0 = w * 32;

  // persistent Q fragments: rows wq0 + i*16, k-groups g*32
  bf16x8 qF[2][6];
#pragma unroll
  for (int i = 0; i < 2; ++i)
#pragma unroll
    for (int g = 0; g < 6; ++g) {
      const int grow = q0 + wq0 + i * 16 + l15;
      union { uint4 u; bf16x8 v; } tmp;
      tmp.u = *(const uint4*)(qh + (size_t)grow * 3072 + h * 192 + g * 32 + quad * 8);
      qF[i][g] = tmp.v;
    }

  f32x4 oA[2][8];
  float mi[2][4], li[2][4];
#pragma unroll
  for (int i = 0; i < 2; ++i) {
#pragma unroll
    for (int r = 0; r < 4; ++r) { mi[i][r] = -1e30f; li[i][r] = 0.f; }
#pragma unroll
    for (int j = 0; j < 8; ++j) { oA[i][j][0] = 0.f; oA[i][j][1] = 0.f; oA[i][j][2] = 0.f; oA[i][j][3] = 0.f; }
  }

  const int nk = 2 * (qt + 1);
  for (int kt = 0; kt < nk; ++kt) {
    const int k0 = kt * 64;
    __syncthreads();   // prev PV reads (sP alias + sVt) done everywhere
    // ---- stage K: 64 keys x 192 (nope 128 from kvb, rope 64 from kpe) ----
    {
      const int key = tid >> 2;            // 4 threads per key
#pragma unroll
      for (int r = 0; r < 6; ++r) {
        const int col = ((tid & 3) + (r << 2)) * 8;   // 0..184
        uint4 d;
        if (col < 128) d = *(const uint4*)(kvb + (size_t)(k0 + key) * 4096 + h * 256 + col);
        else           d = *(const uint4*)(kpe + (size_t)(k0 + key) * 64 + (col - 128));
        *(uint4*)&sK[key * 200 + col] = d;
      }
    }
    // ---- stage V transposed: sVt[n][k], packed b32 writes (k-pairs) ----
#pragma unroll
    for (int r = 0; r < 2; ++r) {
      const int u = tid + (r << 8);
      const int p = u >> 4;               // k-pair 0..31
      const int c = (u & 15) << 3;        // n0
      const unsigned short* v0 = kvb + (size_t)(k0 + 2 * p) * 4096 + h * 256 + 128 + c;
      uint4 a = *(const uint4*)v0;
      uint4 b = *(const uint4*)(v0 + 4096);
      const unsigned short* ap = (const unsigned short*)&a;
      const unsigned short* bp = (const unsigned short*)&b;
#pragma unroll
      for (int e = 0; e < 8; ++e) {
        unsigned int pk = (unsigned int)ap[e] | ((unsigned int)bp[e] << 16);
        *(unsigned int*)&sVt[(c + e) * 72 + 2 * p] = pk;
      }
    }
    __syncthreads();

    // ---- S = Q K^T  (2 row-tiles x 4 col-tiles x 6 k-groups) ----
    f32x4 sc[2][4];
#pragma unroll
    for (int i = 0; i < 2; ++i)
#pragma unroll
      for (int jj = 0; jj < 4; ++jj) { sc[i][jj][0] = 0.f; sc[i][jj][1] = 0.f; sc[i][jj][2] = 0.f; sc[i][jj][3] = 0.f; }
#pragma unroll
    for (int g = 0; g < 6; ++g) {
      bf16x8 kF[4];
#pragma unroll
      for (int jj = 0; jj < 4; ++jj)
        kF[jj] = *(const bf16x8*)&sK[(jj * 16 + l15) * 200 + g * 32 + quad * 8];
#pragma unroll
      for (int i = 0; i < 2; ++i)
#pragma unroll
        for (int jj = 0; jj < 4; ++jj)
          sc[i][jj] = mfma16(qF[i][g], kF[jj], sc[i][jj]);
    }

    // ---- online softmax (rows: quad*4+r; cols: jj*16+l15; reduce over l15 bits) ----
    const bool msk = (kt >= 2 * qt);
#pragma unroll
    for (int i = 0; i < 2; ++i) {
#pragma unroll
      for (int r = 0; r < 4; ++r) {
        const int grow = q0 + wq0 + i * 16 + quad * 4 + r;
        float mx = -1e30f;
#pragma unroll
        for (int jj = 0; jj < 4; ++jj) {
          float v = sc[i][jj][r] * ATT_SCALE;
          if (msk && (k0 + jj * 16 + l15) > grow) v = -1e30f;
          sc[i][jj][r] = v;
          mx = fmaxf(mx, v);
        }
        mx = fmaxf(mx, __shfl_xor(mx, 1, 64));
        mx = fmaxf(mx, __shfl_xor(mx, 2, 64));
        mx = fmaxf(mx, __shfl_xor(mx, 4, 64));
        mx = fmaxf(mx, __shfl_xor(mx, 8, 64));
        const float mnew = fmaxf(mi[i][r], mx);
        const float alpha = __expf(mi[i][r] - mnew);
        float sum = 0.f;
#pragma unroll
        for (int jj = 0; jj < 4; ++jj) {
          float p = __expf(sc[i][jj][r] - mnew);
          sc[i][jj][r] = p;
          sum += p;
        }
        sum += __shfl_xor(sum, 1, 64);
        sum += __shfl_xor(sum, 2, 64);
        sum += __shfl_xor(sum, 4, 64);
        sum += __shfl_xor(sum, 8, 64);
        li[i][r] = li[i][r] * alpha + sum;
        mi[i][r] = mnew;
#pragma unroll
        for (int j = 0; j < 8; ++j) oA[i][j][r] *= alpha;
      }
    }

    __syncthreads();   // all waves done reading sK before P overwrites it
    // ---- write P (bf16) into sP[m][k], m = own 32 rows ----
#pragma unroll
    for (int i = 0; i < 2; ++i)
#pragma unroll
      for (int jj = 0; jj < 4; ++jj)
#pragma unroll
        for (int r = 0; r < 4; ++r)
          sP[(wq0 + i * 16 + quad * 4 + r) * 72 + jj * 16 + l15] = f2bf(sc[i][jj][r]);

    // ---- O += P V  (reads own P rows + shared sVt) ----
#pragma unroll
    for (int ks = 0; ks < 2; ++ks) {
      const int kk0 = ks * 32;
      bf16x8 pF[2], vF[8];
#pragma unroll
      for (int i = 0; i < 2; ++i)
        pF[i] = *(const bf16x8*)&sP[(wq0 + i * 16 + l15) * 72 + kk0 + quad * 8];
#pragma unroll
      for (int j = 0; j < 8; ++j)
        vF[j] = *(const bf16x8*)&sVt[(j * 16 + l15) * 72 + kk0 + quad * 8];
#pragma unroll
      for (int i = 0; i < 2; ++i)
#pragma unroll
        for (int j = 0; j < 8; ++j)
          oA[i][j] = mfma16(pF[i], vF[j], oA[i][j]);
    }
  }

  // ---- epilogue: O / l -> bf16 ----
#pragma unroll
  for (int i = 0; i < 2; ++i)
#pragma unroll
    for (int r = 0; r < 4; ++r) {
      const float inv = 1.f / li[i][r];
      const size_t grow = (size_t)(q0 + wq0 + i * 16 + quad * 4 + r);
#pragma unroll
      for (int j = 0; j < 8; ++j)
        attnh[grow * 2048 + h * 128 + j * 16 + l15] = f2bf(oA[i][j][r] * inv);
    }
}

extern "C" void kernel_launch(void* const* d_in, const int* in_sizes, int n_in,
                              void* d_out, int out_size, void* d_ws, size_t ws_size,
                              hipStream_t stream) {
  const float* x        = (const float*)d_in[0];
  const float* wq       = (const float*)d_in[1];
  const float* wkv_a    = (const float*)d_in[2];
  const float* kv_gamma = (const float*)d_in[3];
  const float* kv_beta  = (const float*)d_in[4];
  const float* wkv_b    = (const float*)d_in[5];
  const float* wo       = (const float*)d_in[6];
  float* out = (float*)d_out;

  char* p = (char*)d_ws;
  unsigned short* xh    = (unsigned short*)p; p += (size_t)4096 * 2048 * 2;
  unsigned short* wqh   = (unsigned short*)p; p += (size_t)3072 * 2048 * 2;
  unsigned short* wah   = (unsigned short*)p; p += (size_t)640 * 2048 * 2;   // padded 576->640
  unsigned short* wbh   = (unsigned short*)p; p += (size_t)4096 * 512 * 2;
  unsigned short* woh   = (unsigned short*)p; p += (size_t)2048 * 2048 * 2;
  unsigned short* qh    = (unsigned short*)p; p += (size_t)4096 * 3072 * 2;
  float*          kvful = (float*)p;          p += (size_t)4096 * 640 * 4;
  unsigned short* kvlnh = (unsigned short*)p; p += (size_t)4096 * 512 * 2;
  unsigned short* kpeh  = (unsigned short*)p; p += (size_t)4096 * 64 * 2;
  unsigned short* kvbh  = (unsigned short*)p; p += (size_t)4096 * 4096 * 2;
  unsigned short* attnh = (unsigned short*)p; p += (size_t)4096 * 2048 * 2;
  if ((size_t)(p - (char*)d_ws) > ws_size) return;

  // casts to bf16 (wah zero-padded)
  cast_bf16<<<8192, 256, 0, stream>>>(x,     xh,  4096 * 2048, 4096 * 2048);
  cast_bf16<<<6144, 256, 0, stream>>>(wq,    wqh, 3072 * 2048, 3072 * 2048);
  cast_bf16<<<1280, 256, 0, stream>>>(wkv_a, wah, 576 * 2048,  640 * 2048);
  cast_bf16<<<2048, 256, 0, stream>>>(wkv_b, wbh, 4096 * 512,  4096 * 512);
  cast_bf16<<<4096, 256, 0, stream>>>(wo,    woh, 2048 * 2048, 2048 * 2048);

  // 1. q = x @ wq^T  -> bf16
  gemm_bf16<true><<<dim3(24, 32), 256, 0, stream>>>(xh, wqh, qh, 4096, 3072, 2048);
  // 2. rope(q_pe) in place
  rope_q_bf<<<8192, 256, 0, stream>>>(qh);
  // 3. kv_full = x @ wkv_a^T -> f32 (LN stats precision), padded N=640
  gemm_bf16<false><<<dim3(5, 32), 256, 0, stream>>>(xh, wah, kvful, 4096, 640, 2048);
  // 4. layernorm + rope(k_pe) -> bf16
  ln_rope_k<<<4096, 256, 0, stream>>>(kvful, kv_gamma, kv_beta, kvlnh, kpeh);
  // 5. kvb = kvln @ wkv_b^T -> bf16
  gemm_bf16<true><<<dim3(32, 32), 256, 0, stream>>>(kvlnh, wbh, kvbh, 4096, 4096, 512);
  // 6. causal MFMA flash attention
  attn_mfma<<<512, 256, 0, stream>>>(qh, kvbh, kpeh, attnh);
  // 7. out = attn @ wo^T -> f32
  gemm_bf16<false><<<dim3(16, 32), 256, 0, stream>>>(attnh, woh, out, 4096, 2048, 2048);
}

// Round 3
// 660.626 us; speedup vs baseline: 7.5478x; 1.0618x over previous
//
#include <hip/hip_runtime.h>
#include <hip/hip_bf16.h>

typedef __attribute__((ext_vector_type(8))) short bf16x8;
typedef __attribute__((ext_vector_type(4))) float f32x4;
typedef __attribute__((address_space(3))) unsigned int lds_u32;
typedef __attribute__((address_space(1))) const unsigned int glb_u32;

#define LOG2_10000 13.287712379549449f
#define QSCALE (0.07216878364870323f * 1.4426950408889634f)  // 192^-0.5 * log2(e)

static __device__ __forceinline__ unsigned short f2bf(float f) {
  union { float f; unsigned int u; } v; v.f = f;
  unsigned int r = v.u + 0x7FFFu + ((v.u >> 16) & 1u);
  return (unsigned short)(r >> 16);
}
static __device__ __forceinline__ float bf2f(unsigned short h) {
  union { unsigned int u; float f; } v; v.u = ((unsigned int)h) << 16;
  return v.f;
}
static __device__ __forceinline__ f32x4 mfma16(bf16x8 a, bf16x8 b, f32x4 c) {
  return __builtin_amdgcn_mfma_f32_16x16x32_bf16(a, b, c, 0, 0, 0);
}
static __device__ __forceinline__ void gl_lds16(const void* g, void* l) {
  __builtin_amdgcn_global_load_lds((glb_u32*)g, (lds_u32*)l, 16, 0, 0);
}

// ---------- cast f32 -> bf16 with trailing zero-fill (pad region) ----------
__global__ __launch_bounds__(256) void cast_bf16(const float* __restrict__ src,
                                                 unsigned short* __restrict__ dst,
                                                 int nsrc, int ndst) {
  int i = (blockIdx.x * 256 + threadIdx.x) * 4;
  if (i >= ndst) return;
  float4 v = make_float4(0.f, 0.f, 0.f, 0.f);
  if (i < nsrc) v = *(const float4*)(src + i);
  uint2 o;
  o.x = (unsigned int)f2bf(v.x) | ((unsigned int)f2bf(v.y) << 16);
  o.y = (unsigned int)f2bf(v.z) | ((unsigned int)f2bf(v.w) << 16);
  *(uint2*)(dst + i) = o;
}

// ---------- bf16 NT GEMM: C[M,N] = alpha * A[M,K] * Bt[N,K]^T ----------
template <bool OUTBF>
__global__ __launch_bounds__(256, 2) void gemm_bf16(const unsigned short* __restrict__ A,
                                                    const unsigned short* __restrict__ Bt,
                                                    void* __restrict__ Cv,
                                                    int M, int N, int K, float alpha) {
  __shared__ unsigned short As[128 * 32];
  __shared__ unsigned short Bs[128 * 32];
  const int tid = threadIdx.x;
  const int w = tid >> 6, lane = tid & 63;
  const int quad = lane >> 4, l15 = lane & 15;
  const int wx = w & 1, wy = w >> 1;
  const int bm = blockIdx.y * 128, bn = blockIdx.x * 128;

  f32x4 acc[4][4];
#pragma unroll
  for (int i = 0; i < 4; ++i)
#pragma unroll
    for (int j = 0; j < 4; ++j) { acc[i][j][0] = 0.f; acc[i][j][1] = 0.f; acc[i][j][2] = 0.f; acc[i][j][3] = 0.f; }

  const int lrow = lane >> 2;
  const int lcol = (lane & 3) * 8;
  const unsigned short* Ag = A + (size_t)(bm + w * 16 + lrow) * K + lcol;
  const unsigned short* Bg = Bt + (size_t)(bn + w * 16 + lrow) * K + lcol;
  unsigned short* AsB = &As[(w * 16) * 32];
  unsigned short* BsB = &Bs[(w * 16) * 32];

  for (int k0 = 0; k0 < K; k0 += 32) {
    __syncthreads();
    gl_lds16(Ag + k0, AsB);
    gl_lds16(Ag + (size_t)64 * K + k0, AsB + 64 * 32);
    gl_lds16(Bg + k0, BsB);
    gl_lds16(Bg + (size_t)64 * K + k0, BsB + 64 * 32);
    __syncthreads();
    bf16x8 aF[4], bF[4];
#pragma unroll
    for (int i = 0; i < 4; ++i)
      aF[i] = *(const bf16x8*)&As[(wy * 64 + i * 16 + l15) * 32 + quad * 8];
#pragma unroll
    for (int j = 0; j < 4; ++j)
      bF[j] = *(const bf16x8*)&Bs[(wx * 64 + j * 16 + l15) * 32 + quad * 8];
#pragma unroll
    for (int i = 0; i < 4; ++i)
#pragma unroll
      for (int j = 0; j < 4; ++j)
        acc[i][j] = mfma16(aF[i], bF[j], acc[i][j]);
  }

#pragma unroll
  for (int i = 0; i < 4; ++i)
#pragma unroll
    for (int r = 0; r < 4; ++r) {
      const size_t row = (size_t)(bm + wy * 64 + i * 16 + quad * 4 + r) * (size_t)N;
#pragma unroll
      for (int j = 0; j < 4; ++j) {
        const int col = bn + wx * 64 + j * 16 + l15;
        if (OUTBF) ((unsigned short*)Cv)[row + col] = f2bf(acc[i][j][r] * alpha);
        else       ((float*)Cv)[row + col] = acc[i][j][r];
      }
    }
}

// ---------- RoPE on q_pe, in place on bf16 q (values pre-scaled; rotation preserves scale) ----------
__global__ __launch_bounds__(256) void rope_q_bf(unsigned short* __restrict__ qh) {
  int idx = blockIdx.x * 256 + threadIdx.x;
  int j = idx & 31;
  int th = idx >> 5;
  int h = th & 15;
  int t = th >> 4;
  float fr = exp2f(-(float)j * (LOG2_10000 / 32.f));
  float ang = (float)t * fr;
  float sn, cs;
  sincosf(ang, &sn, &cs);
  unsigned short* p = qh + (size_t)t * 3072 + h * 192 + 128 + 2 * j;
  unsigned int v = *(unsigned int*)p;
  float a = bf2f((unsigned short)v), b = bf2f((unsigned short)(v >> 16));
  float na = a * cs - b * sn, nb = a * sn + b * cs;
  *(unsigned int*)p = (unsigned int)f2bf(na) | ((unsigned int)f2bf(nb) << 16);
}

// ---------- LayerNorm(kv) + RoPE(k_pe); f32 in (stride 640), bf16 out ----------
__global__ __launch_bounds__(256) void ln_rope_k(const float* __restrict__ kvfull,
                                                 const float* __restrict__ gamma,
                                                 const float* __restrict__ beta,
                                                 unsigned short* __restrict__ kvln,
                                                 unsigned short* __restrict__ kpe) {
  const int t = blockIdx.x;
  const int tid = threadIdx.x;
  const float* row = kvfull + (size_t)t * 640;
  float x0 = row[tid], x1 = row[tid + 256];
  float sm = x0 + x1;
  float sq = x0 * x0 + x1 * x1;
#pragma unroll
  for (int off = 1; off < 64; off <<= 1) {
    sm += __shfl_xor(sm, off, 64);
    sq += __shfl_xor(sq, off, 64);
  }
  __shared__ float rs[4], rq[4];
  const int lane = tid & 63, wid = tid >> 6;
  if (lane == 0) { rs[wid] = sm; rq[wid] = sq; }
  __syncthreads();
  float tsm = rs[0] + rs[1] + rs[2] + rs[3];
  float tsq = rq[0] + rq[1] + rq[2] + rq[3];
  float mu = tsm * (1.f / 512.f);
  float var = tsq * (1.f / 512.f) - mu * mu;
  float inv = rsqrtf(var + 1e-5f);
  kvln[(size_t)t * 512 + tid]       = f2bf((x0 - mu) * inv * gamma[tid] + beta[tid]);
  kvln[(size_t)t * 512 + tid + 256] = f2bf((x1 - mu) * inv * gamma[tid + 256] + beta[tid + 256]);
  if (tid < 32) {
    float a = row[512 + 2 * tid], b = row[512 + 2 * tid + 1];
    float fr = exp2f(-(float)tid * (LOG2_10000 / 32.f));
    float ang = (float)t * fr;
    float sn, cs;
    sincosf(ang, &sn, &cs);
    kpe[(size_t)t * 64 + 2 * tid]     = f2bf(a * cs - b * sn);
    kpe[(size_t)t * 64 + 2 * tid + 1] = f2bf(a * sn + b * cs);
  }
}

// ---------- MFMA flash attention v2 ----------
// qh pre-scaled by QSCALE.  LDS: sK = 6 panels [64 keys][32 shorts] (global_load_lds
// layout, m97 bank pattern), sVt[128 n][72 k-pad] (V^T), sP per-wave [32][72].
// 2 barriers per K-step.  exp2-domain softmax.
__global__ __launch_bounds__(256, 2) void attn_mfma(const unsigned short* __restrict__ qh,
                                                    const unsigned short* __restrict__ kvb,
                                                    const unsigned short* __restrict__ kpe,
                                                    unsigned short* __restrict__ attnh) {
  __shared__ unsigned short sK[6 * 2048];      // 24 KB
  __shared__ unsigned short sVt[128 * 72];     // 18 KB
  __shared__ unsigned short sP[4 * 32 * 72];   // 18 KB, per-wave private slabs

  const int bid = blockIdx.x;
  const int h = bid & 15;
  const int z = bid >> 4;                       // 0..31
  const int qt = (z < 16) ? (31 - z) : (z - 16);  // heavy blocks first; pairs sum to 31
  const int q0 = qt * 128;
  const int tid = threadIdx.x;
  const int w = tid >> 6, lane = tid & 63;
  const int quad = lane >> 4, l15 = lane & 15;
  const int wq0 = w * 32;
  unsigned short* sPw = &sP[w * 32 * 72];

  const unsigned short* kvbh = kvb + h * 256;

  // persistent Q fragments (pre-scaled by QSCALE at GEMM epilogue)
  bf16x8 qF[2][6];
#pragma unroll
  for (int i = 0; i < 2; ++i)
#pragma unroll
    for (int g = 0; g < 6; ++g) {
      const int grow = q0 + wq0 + i * 16 + l15;
      union { uint4 u; bf16x8 v; } tmp;
      tmp.u = *(const uint4*)(qh + (size_t)grow * 3072 + h * 192 + g * 32 + quad * 8);
      qF[i][g] = tmp.v;
    }

  f32x4 oA[2][8];
  float mi[2][4], li[2][4];
#pragma unroll
  for (int i = 0; i < 2; ++i) {
#pragma unroll
    for (int r = 0; r < 4; ++r) { mi[i][r] = -1e30f; li[i][r] = 0.f; }
#pragma unroll
    for (int j = 0; j < 8; ++j) { oA[i][j][0] = 0.f; oA[i][j][1] = 0.f; oA[i][j][2] = 0.f; oA[i][j][3] = 0.f; }
  }

  // V-gather thread mapping: lane-low-5 = k-pair -> all 32 banks on LDS writes
  const int vp  = tid & 31;          // k-pair 0..31
  const int vc8 = tid >> 5;          // 0..7 (r adds 8)

  const int nk = 2 * (qt + 1);
  for (int kt = 0; kt < nk; ++kt) {
    const int k0 = kt * 64;
    __syncthreads();   // prev iter: S-reads of sK, PV-reads of sVt complete

    // ---- stage K via global_load_lds: panel layout, 6 instrs/wave ----
#pragma unroll
    for (int j = 0; j < 6; ++j) {
      const int i = w * 6 + j;
      const int granule = i * 64 + lane;
      const int g  = granule >> 8;
      const int key = (granule >> 2) & 63;
      const int col = (g << 5) + ((granule & 3) << 3);   // shorts
      const unsigned short* src = (col < 128)
          ? kvbh + (size_t)(k0 + key) * 4096 + col
          : kpe + (size_t)(k0 + key) * 64 + (col - 128);
      gl_lds16(src, &sK[i * 512]);
    }

    // ---- stage V^T: 16B gathers, packed b32 writes (conflict-free mapping) ----
#pragma unroll
    for (int r = 0; r < 2; ++r) {
      const int c8 = vc8 + r * 8;          // 0..15 -> n-block
      const unsigned short* v0 = kvbh + (size_t)(k0 + 2 * vp) * 4096 + 128 + c8 * 8;
      uint4 a = *(const uint4*)v0;
      uint4 b = *(const uint4*)(v0 + 4096);
      unsigned int* dst = (unsigned int*)&sVt[(size_t)(c8 * 8) * 72 + 2 * vp];
      const unsigned int aa[4] = {a.x, a.y, a.z, a.w};
      const unsigned int bb[4] = {b.x, b.y, b.z, b.w};
#pragma unroll
      for (int q = 0; q < 4; ++q) {
        dst[(2 * q) * 36]     = (aa[q] & 0xFFFFu) | (bb[q] << 16);
        dst[(2 * q + 1) * 36] = (aa[q] >> 16) | (bb[q] & 0xFFFF0000u);
      }
    }
    __syncthreads();   // staging visible (drains global_load_lds + ds writes)

    // ---- S = Q K^T ----
    f32x4 sc[2][4];
#pragma unroll
    for (int i = 0; i < 2; ++i)
#pragma unroll
      for (int jj = 0; jj < 4; ++jj) { sc[i][jj][0] = 0.f; sc[i][jj][1] = 0.f; sc[i][jj][2] = 0.f; sc[i][jj][3] = 0.f; }
#pragma unroll
    for (int g = 0; g < 6; ++g) {
      bf16x8 kF[4];
#pragma unroll
      for (int jj = 0; jj < 4; ++jj)
        kF[jj] = *(const bf16x8*)&sK[g * 2048 + (jj * 16 + l15) * 32 + quad * 8];
#pragma unroll
      for (int i = 0; i < 2; ++i)
#pragma unroll
        for (int jj = 0; jj < 4; ++jj)
          sc[i][jj] = mfma16(qF[i][g], kF[jj], sc[i][jj]);
    }

    // ---- online softmax (exp2 domain; scores pre-scaled) ----
    const bool msk = (kt >= 2 * qt);
#pragma unroll
    for (int i = 0; i < 2; ++i) {
#pragma unroll
      for (int r = 0; r < 4; ++r) {
        float mx = -1e30f;
        if (msk) {
          const int grow = q0 + wq0 + i * 16 + quad * 4 + r;
#pragma unroll
          for (int jj = 0; jj < 4; ++jj) {
            float v = sc[i][jj][r];
            if ((k0 + jj * 16 + l15) > grow) v = -1e30f;
            sc[i][jj][r] = v;
            mx = fmaxf(mx, v);
          }
        } else {
#pragma unroll
          for (int jj = 0; jj < 4; ++jj) mx = fmaxf(mx, sc[i][jj][r]);
        }
        mx = fmaxf(mx, __shfl_xor(mx, 1, 64));
        mx = fmaxf(mx, __shfl_xor(mx, 2, 64));
        mx = fmaxf(mx, __shfl_xor(mx, 4, 64));
        mx = fmaxf(mx, __shfl_xor(mx, 8, 64));
        const float mnew = fmaxf(mi[i][r], mx);
        const float alpha = __builtin_amdgcn_exp2f(mi[i][r] - mnew);
        float sum = 0.f;
#pragma unroll
        for (int jj = 0; jj < 4; ++jj) {
          float p = __builtin_amdgcn_exp2f(sc[i][jj][r] - mnew);
          sc[i][jj][r] = p;
          sum += p;
        }
        sum += __shfl_xor(sum, 1, 64);
        sum += __shfl_xor(sum, 2, 64);
        sum += __shfl_xor(sum, 4, 64);
        sum += __shfl_xor(sum, 8, 64);
        li[i][r] = li[i][r] * alpha + sum;
        mi[i][r] = mnew;
#pragma unroll
        for (int j = 0; j < 8; ++j) oA[i][j][r] *= alpha;
      }
    }

    // ---- write P into per-wave slab (truncation: P in [0,1], error << tolerance) ----
#pragma unroll
    for (int i = 0; i < 2; ++i)
#pragma unroll
      for (int jj = 0; jj < 4; ++jj)
#pragma unroll
        for (int r = 0; r < 4; ++r) {
          union { float f; unsigned int u; } pv; pv.f = sc[i][jj][r];
          sPw[(i * 16 + quad * 4 + r) * 72 + jj * 16 + l15] = (unsigned short)(pv.u >> 16);
        }

    // ---- O += P V (own sP slab: no barrier needed; sVt covered by post-stage barrier) ----
#pragma unroll
    for (int ks = 0; ks < 2; ++ks) {
      const int kk0 = ks * 32;
      bf16x8 pF[2], vF[8];
#pragma unroll
      for (int i = 0; i < 2; ++i)
        pF[i] = *(const bf16x8*)&sPw[(i * 16 + l15) * 72 + kk0 + quad * 8];
#pragma unroll
      for (int j = 0; j < 8; ++j)
        vF[j] = *(const bf16x8*)&sVt[(j * 16 + l15) * 72 + kk0 + quad * 8];
#pragma unroll
      for (int i = 0; i < 2; ++i)
#pragma unroll
        for (int j = 0; j < 8; ++j)
          oA[i][j] = mfma16(pF[i], vF[j], oA[i][j]);
    }
  }

  // ---- epilogue ----
#pragma unroll
  for (int i = 0; i < 2; ++i)
#pragma unroll
    for (int r = 0; r < 4; ++r) {
      const float inv = 1.f / li[i][r];
      const size_t grow = (size_t)(q0 + wq0 + i * 16 + quad * 4 + r);
#pragma unroll
      for (int j = 0; j < 8; ++j)
        attnh[grow * 2048 + h * 128 + j * 16 + l15] = f2bf(oA[i][j][r] * inv);
    }
}

extern "C" void kernel_launch(void* const* d_in, const int* in_sizes, int n_in,
                              void* d_out, int out_size, void* d_ws, size_t ws_size,
                              hipStream_t stream) {
  const float* x        = (const float*)d_in[0];
  const float* wq       = (const float*)d_in[1];
  const float* wkv_a    = (const float*)d_in[2];
  const float* kv_gamma = (const float*)d_in[3];
  const float* kv_beta  = (const float*)d_in[4];
  const float* wkv_b    = (const float*)d_in[5];
  const float* wo       = (const float*)d_in[6];
  float* out = (float*)d_out;

  char* p = (char*)d_ws;
  unsigned short* xh    = (unsigned short*)p; p += (size_t)4096 * 2048 * 2;
  unsigned short* wqh   = (unsigned short*)p; p += (size_t)3072 * 2048 * 2;
  unsigned short* wah   = (unsigned short*)p; p += (size_t)640 * 2048 * 2;
  unsigned short* wbh   = (unsigned short*)p; p += (size_t)4096 * 512 * 2;
  unsigned short* woh   = (unsigned short*)p; p += (size_t)2048 * 2048 * 2;
  unsigned short* qh    = (unsigned short*)p; p += (size_t)4096 * 3072 * 2;
  float*          kvful = (float*)p;          p += (size_t)4096 * 640 * 4;
  unsigned short* kvlnh = (unsigned short*)p; p += (size_t)4096 * 512 * 2;
  unsigned short* kpeh  = (unsigned short*)p; p += (size_t)4096 * 64 * 2;
  unsigned short* kvbh  = (unsigned short*)p; p += (size_t)4096 * 4096 * 2;
  unsigned short* attnh = (unsigned short*)p; p += (size_t)4096 * 2048 * 2;
  if ((size_t)(p - (char*)d_ws) > ws_size) return;

  cast_bf16<<<8192, 256, 0, stream>>>(x,     xh,  4096 * 2048, 4096 * 2048);
  cast_bf16<<<6144, 256, 0, stream>>>(wq,    wqh, 3072 * 2048, 3072 * 2048);
  cast_bf16<<<1280, 256, 0, stream>>>(wkv_a, wah, 576 * 2048,  640 * 2048);
  cast_bf16<<<2048, 256, 0, stream>>>(wkv_b, wbh, 4096 * 512,  4096 * 512);
  cast_bf16<<<4096, 256, 0, stream>>>(wo,    woh, 2048 * 2048, 2048 * 2048);

  // 1. q = QSCALE * (x @ wq^T) -> bf16 (scale folded: attention works in exp2 domain)
  gemm_bf16<true><<<dim3(24, 32), 256, 0, stream>>>(xh, wqh, qh, 4096, 3072, 2048, QSCALE);
  // 2. rope(q_pe) in place
  rope_q_bf<<<8192, 256, 0, stream>>>(qh);
  // 3. kv_full = x @ wkv_a^T -> f32 (LN stats precision), padded N=640
  gemm_bf16<false><<<dim3(5, 32), 256, 0, stream>>>(xh, wah, kvful, 4096, 640, 2048, 1.f);
  // 4. layernorm + rope(k_pe) -> bf16
  ln_rope_k<<<4096, 256, 0, stream>>>(kvful, kv_gamma, kv_beta, kvlnh, kpeh);
  // 5. kvb = kvln @ wkv_b^T -> bf16
  gemm_bf16<true><<<dim3(32, 32), 256, 0, stream>>>(kvlnh, wbh, kvbh, 4096, 4096, 512, 1.f);
  // 6. causal MFMA flash attention
  attn_mfma<<<512, 256, 0, stream>>>(qh, kvbh, kpeh, attnh);
  // 7. out = attn @ wo^T -> f32
  gemm_bf16<false><<<dim3(16, 32), 256, 0, stream>>>(attnh, woh, out, 4096, 2048, 2048, 1.f);
}

// Round 4
// 493.650 us; speedup vs baseline: 10.1008x; 1.3382x over previous
//
#include <hip/hip_runtime.h>
#include <hip/hip_bf16.h>

typedef __attribute__((ext_vector_type(8))) short bf16x8;
typedef __attribute__((ext_vector_type(4))) float f32x4;
typedef __attribute__((address_space(3))) unsigned int lds_u32;
typedef __attribute__((address_space(1))) const unsigned int glb_u32;

#define LOG2_10000 13.287712379549449f
#define QSCALE (0.07216878364870323f * 1.4426950408889634f)  // 192^-0.5 * log2(e)

static __device__ __forceinline__ unsigned short f2bf(float f) {
  union { float f; unsigned int u; } v; v.f = f;
  unsigned int r = v.u + 0x7FFFu + ((v.u >> 16) & 1u);
  return (unsigned short)(r >> 16);
}
static __device__ __forceinline__ float bf2f(unsigned short h) {
  union { unsigned int u; float f; } v; v.u = ((unsigned int)h) << 16;
  return v.f;
}
static __device__ __forceinline__ f32x4 mfma16(bf16x8 a, bf16x8 b, f32x4 c) {
  return __builtin_amdgcn_mfma_f32_16x16x32_bf16(a, b, c, 0, 0, 0);
}
static __device__ __forceinline__ void gl_lds16(const void* g, void* l) {
  __builtin_amdgcn_global_load_lds((glb_u32*)g, (lds_u32*)l, 16, 0, 0);
}

// ---------- cast f32 -> bf16 with trailing zero-fill (pad region) ----------
__global__ __launch_bounds__(256) void cast_bf16(const float* __restrict__ src,
                                                 unsigned short* __restrict__ dst,
                                                 int nsrc, int ndst) {
  int i = (blockIdx.x * 256 + threadIdx.x) * 4;
  if (i >= ndst) return;
  float4 v = make_float4(0.f, 0.f, 0.f, 0.f);
  if (i < nsrc) v = *(const float4*)(src + i);
  uint2 o;
  o.x = (unsigned int)f2bf(v.x) | ((unsigned int)f2bf(v.y) << 16);
  o.y = (unsigned int)f2bf(v.z) | ((unsigned int)f2bf(v.w) << 16);
  *(uint2*)(dst + i) = o;
}

// ---------- bf16 NT GEMM: C[M,N] = alpha * A[M,K] * Bt[N,K]^T ----------
template <bool OUTBF>
__global__ __launch_bounds__(256, 2) void gemm_bf16(const unsigned short* __restrict__ A,
                                                    const unsigned short* __restrict__ Bt,
                                                    void* __restrict__ Cv,
                                                    int M, int N, int K, float alpha) {
  __shared__ unsigned short As[128 * 32];
  __shared__ unsigned short Bs[128 * 32];
  const int tid = threadIdx.x;
  const int w = tid >> 6, lane = tid & 63;
  const int quad = lane >> 4, l15 = lane & 15;
  const int wx = w & 1, wy = w >> 1;
  const int bm = blockIdx.y * 128, bn = blockIdx.x * 128;

  f32x4 acc[4][4];
#pragma unroll
  for (int i = 0; i < 4; ++i)
#pragma unroll
    for (int j = 0; j < 4; ++j) { acc[i][j][0] = 0.f; acc[i][j][1] = 0.f; acc[i][j][2] = 0.f; acc[i][j][3] = 0.f; }

  const int lrow = lane >> 2;
  const int lcol = (lane & 3) * 8;
  const unsigned short* Ag = A + (size_t)(bm + w * 16 + lrow) * K + lcol;
  const unsigned short* Bg = Bt + (size_t)(bn + w * 16 + lrow) * K + lcol;
  unsigned short* AsB = &As[(w * 16) * 32];
  unsigned short* BsB = &Bs[(w * 16) * 32];

  for (int k0 = 0; k0 < K; k0 += 32) {
    __syncthreads();
    gl_lds16(Ag + k0, AsB);
    gl_lds16(Ag + (size_t)64 * K + k0, AsB + 64 * 32);
    gl_lds16(Bg + k0, BsB);
    gl_lds16(Bg + (size_t)64 * K + k0, BsB + 64 * 32);
    __syncthreads();
    bf16x8 aF[4], bF[4];
#pragma unroll
    for (int i = 0; i < 4; ++i)
      aF[i] = *(const bf16x8*)&As[(wy * 64 + i * 16 + l15) * 32 + quad * 8];
#pragma unroll
    for (int j = 0; j < 4; ++j)
      bF[j] = *(const bf16x8*)&Bs[(wx * 64 + j * 16 + l15) * 32 + quad * 8];
#pragma unroll
    for (int i = 0; i < 4; ++i)
#pragma unroll
      for (int j = 0; j < 4; ++j)
        acc[i][j] = mfma16(aF[i], bF[j], acc[i][j]);
  }

#pragma unroll
  for (int i = 0; i < 4; ++i)
#pragma unroll
    for (int r = 0; r < 4; ++r) {
      const size_t row = (size_t)(bm + wy * 64 + i * 16 + quad * 4 + r) * (size_t)N;
#pragma unroll
      for (int j = 0; j < 4; ++j) {
        const int col = bn + wx * 64 + j * 16 + l15;
        if (OUTBF) ((unsigned short*)Cv)[row + col] = f2bf(acc[i][j][r] * alpha);
        else       ((float*)Cv)[row + col] = acc[i][j][r];
      }
    }
}

// ---------- RoPE on q_pe, in place on bf16 q ----------
__global__ __launch_bounds__(256) void rope_q_bf(unsigned short* __restrict__ qh) {
  int idx = blockIdx.x * 256 + threadIdx.x;
  int j = idx & 31;
  int th = idx >> 5;
  int h = th & 15;
  int t = th >> 4;
  float fr = exp2f(-(float)j * (LOG2_10000 / 32.f));
  float ang = (float)t * fr;
  float sn, cs;
  sincosf(ang, &sn, &cs);
  unsigned short* p = qh + (size_t)t * 3072 + h * 192 + 128 + 2 * j;
  unsigned int v = *(unsigned int*)p;
  float a = bf2f((unsigned short)v), b = bf2f((unsigned short)(v >> 16));
  float na = a * cs - b * sn, nb = a * sn + b * cs;
  *(unsigned int*)p = (unsigned int)f2bf(na) | ((unsigned int)f2bf(nb) << 16);
}

// ---------- LayerNorm(kv) + RoPE(k_pe); f32 in (stride 640), bf16 out ----------
__global__ __launch_bounds__(256) void ln_rope_k(const float* __restrict__ kvfull,
                                                 const float* __restrict__ gamma,
                                                 const float* __restrict__ beta,
                                                 unsigned short* __restrict__ kvln,
                                                 unsigned short* __restrict__ kpe) {
  const int t = blockIdx.x;
  const int tid = threadIdx.x;
  const float* row = kvfull + (size_t)t * 640;
  float x0 = row[tid], x1 = row[tid + 256];
  float sm = x0 + x1;
  float sq = x0 * x0 + x1 * x1;
#pragma unroll
  for (int off = 1; off < 64; off <<= 1) {
    sm += __shfl_xor(sm, off, 64);
    sq += __shfl_xor(sq, off, 64);
  }
  __shared__ float rs[4], rq[4];
  const int lane = tid & 63, wid = tid >> 6;
  if (lane == 0) { rs[wid] = sm; rq[wid] = sq; }
  __syncthreads();
  float tsm = rs[0] + rs[1] + rs[2] + rs[3];
  float tsq = rq[0] + rq[1] + rq[2] + rq[3];
  float mu = tsm * (1.f / 512.f);
  float var = tsq * (1.f / 512.f) - mu * mu;
  float inv = rsqrtf(var + 1e-5f);
  kvln[(size_t)t * 512 + tid]       = f2bf((x0 - mu) * inv * gamma[tid] + beta[tid]);
  kvln[(size_t)t * 512 + tid + 256] = f2bf((x1 - mu) * inv * gamma[tid + 256] + beta[tid + 256]);
  if (tid < 32) {
    float a = row[512 + 2 * tid], b = row[512 + 2 * tid + 1];
    float fr = exp2f(-(float)tid * (LOG2_10000 / 32.f));
    float ang = (float)t * fr;
    float sn, cs;
    sincosf(ang, &sn, &cs);
    kpe[(size_t)t * 64 + 2 * tid]     = f2bf(a * cs - b * sn);
    kpe[(size_t)t * 64 + 2 * tid + 1] = f2bf(a * sn + b * cs);
  }
}

// ---------- V transpose: kvb[t][h*256+128+c] -> Vt[h][c][t] ----------
__global__ __launch_bounds__(256) void transpose_v(const unsigned short* __restrict__ kvb,
                                                   unsigned short* __restrict__ Vt) {
  __shared__ unsigned short tile[64][72];
  const int tb = blockIdx.x * 64;
  const int h  = blockIdx.y >> 1;
  const int c0 = (blockIdx.y & 1) * 64;
  const int tid = threadIdx.x;
  const int r  = tid >> 4;
  const int c4 = (tid & 15) * 4;
#pragma unroll
  for (int rep = 0; rep < 4; ++rep) {
    const int t = rep * 16 + r;
    uint2 d = *(const uint2*)(kvb + (size_t)(tb + t) * 4096 + h * 256 + 128 + c0 + c4);
    *(uint2*)&tile[t][c4] = d;
  }
  __syncthreads();
#pragma unroll
  for (int rep = 0; rep < 4; ++rep) {
    const int c = rep * 16 + r;
    unsigned int lo = (unsigned int)tile[c4 + 0][c] | ((unsigned int)tile[c4 + 1][c] << 16);
    unsigned int hi = (unsigned int)tile[c4 + 2][c] | ((unsigned int)tile[c4 + 3][c] << 16);
    uint2 o; o.x = lo; o.y = hi;
    *(uint2*)(Vt + ((size_t)h * 128 + c0 + c) * 4096 + tb + c4) = o;
  }
}

// ---------- MFMA flash attention v3 ----------
// S computed transposed (A=K, B=Q): softmax = in-lane + 2 shfls; P written as
// packed b64.  V staged from pre-transposed Vt via async global_load_lds with
// XOR-swizzled destination (stride-64, conflict-free b128 reads).
__global__ __launch_bounds__(256, 2) void attn_mfma(const unsigned short* __restrict__ qh,
                                                    const unsigned short* __restrict__ kvb,
                                                    const unsigned short* __restrict__ kpe,
                                                    const unsigned short* __restrict__ Vt,
                                                    unsigned short* __restrict__ attnh) {
  __shared__ unsigned short sK[6 * 2048];     // 24 KB: 6 panels [64 keys][32]
  __shared__ unsigned short sVt[128 * 64];    // 16 KB: swizzled (8-blocks ^ row&7)
  __shared__ unsigned short sP[128 * 72];     // 18 KB: [m][k], per-wave row slices

  const int bid = blockIdx.x;
  const int h = bid & 15;
  const int z = bid >> 4;
  const int qt = (z < 16) ? (31 - z) : (z - 16);
  const int q0 = qt * 128;
  const int tid = threadIdx.x;
  const int w = tid >> 6, lane = tid & 63;
  const int quad = lane >> 4, l15 = lane & 15;
  const int wq0 = w * 32;

  const unsigned short* kvbh = kvb + h * 256;
  const unsigned short* Vth = Vt + (size_t)h * 128 * 4096;

  // Q fragments (B-operand: lane l15 = q-row m)
  bf16x8 qF[2][6];
#pragma unroll
  for (int i = 0; i < 2; ++i)
#pragma unroll
    for (int g = 0; g < 6; ++g) {
      const int grow = q0 + wq0 + i * 16 + l15;
      union { uint4 u; bf16x8 v; } tmp;
      tmp.u = *(const uint4*)(qh + (size_t)grow * 3072 + h * 192 + g * 32 + quad * 8);
      qF[i][g] = tmp.v;
    }

  f32x4 oA[2][8];
  float mi[2], li[2];   // per lane: row m = i*16 + l15 (replicated across quads)
#pragma unroll
  for (int i = 0; i < 2; ++i) {
    mi[i] = -1e30f; li[i] = 0.f;
#pragma unroll
    for (int j = 0; j < 8; ++j) { oA[i][j][0] = 0.f; oA[i][j][1] = 0.f; oA[i][j][2] = 0.f; oA[i][j][3] = 0.f; }
  }

  const int nk = 2 * (qt + 1);
  for (int kt = 0; kt < nk; ++kt) {
    const int k0 = kt * 64;
    __syncthreads();   // prev iter: S reads of sK, PV reads of sVt complete

    // ---- stage K: 6 async gl_lds per wave (panel layout) ----
#pragma unroll
    for (int j = 0; j < 6; ++j) {
      const int i = w * 6 + j;
      const int granule = i * 64 + lane;
      const int g = granule >> 8;
      const int key = (granule >> 2) & 63;
      const int col = (g << 5) + ((granule & 3) << 3);
      const unsigned short* src = (col < 128)
          ? kvbh + (size_t)(k0 + key) * 4096 + col
          : kpe + (size_t)(k0 + key) * 64 + (col - 128);
      gl_lds16(src, &sK[i * 512]);
    }
    // ---- stage V^T: 4 async gl_lds per wave, XOR-swizzled dest ----
#pragma unroll
    for (int j = 0; j < 4; ++j) {
      const int ii = w * 4 + j;
      const int n = ii * 8 + (lane >> 3);
      const int b = (lane & 7) ^ ((lane >> 3) & 7);
      gl_lds16(Vth + (size_t)n * 4096 + k0 + b * 8, &sVt[ii * 512]);
    }
    __syncthreads();   // staging visible

    // ---- S^T = K Q^T: sc[kk][i], D row = key(quad*4+r), col = m(l15) ----
    f32x4 sc[4][2];
#pragma unroll
    for (int kk = 0; kk < 4; ++kk)
#pragma unroll
      for (int i = 0; i < 2; ++i) { sc[kk][i][0] = 0.f; sc[kk][i][1] = 0.f; sc[kk][i][2] = 0.f; sc[kk][i][3] = 0.f; }
#pragma unroll
    for (int g = 0; g < 6; ++g) {
      bf16x8 kF[4];
#pragma unroll
      for (int kk = 0; kk < 4; ++kk)
        kF[kk] = *(const bf16x8*)&sK[g * 2048 + (kk * 16 + l15) * 32 + quad * 8];
#pragma unroll
      for (int kk = 0; kk < 4; ++kk)
#pragma unroll
        for (int i = 0; i < 2; ++i)
          sc[kk][i] = mfma16(kF[kk], qF[i][g], sc[kk][i]);
    }

    // ---- online softmax over keys (in-lane 16 + shfl_xor 16,32) ----
    const bool msk = (kt >= 2 * qt);
    float alpha[2];
#pragma unroll
    for (int i = 0; i < 2; ++i) {
      const int grow = q0 + wq0 + i * 16 + l15;
      if (msk) {
#pragma unroll
        for (int kk = 0; kk < 4; ++kk)
#pragma unroll
          for (int rr = 0; rr < 4; ++rr) {
            const int gk = k0 + kk * 16 + quad * 4 + rr;
            if (gk > grow) sc[kk][i][rr] = -1e30f;
          }
      }
      float mx = -1e30f;
#pragma unroll
      for (int kk = 0; kk < 4; ++kk)
#pragma unroll
        for (int rr = 0; rr < 4; ++rr) mx = fmaxf(mx, sc[kk][i][rr]);
      mx = fmaxf(mx, __shfl_xor(mx, 16, 64));
      mx = fmaxf(mx, __shfl_xor(mx, 32, 64));
      const float mnew = fmaxf(mi[i], mx);
      alpha[i] = __builtin_amdgcn_exp2f(mi[i] - mnew);
      float sum = 0.f;
#pragma unroll
      for (int kk = 0; kk < 4; ++kk)
#pragma unroll
        for (int rr = 0; rr < 4; ++rr) {
          const float p = __builtin_amdgcn_exp2f(sc[kk][i][rr] - mnew);
          sc[kk][i][rr] = p;
          sum += p;
        }
      sum += __shfl_xor(sum, 16, 64);
      sum += __shfl_xor(sum, 32, 64);
      li[i] = li[i] * alpha[i] + sum;
      mi[i] = mnew;
    }

    // ---- rescale O (alpha fetched to C-layout rows: 8 shfls) ----
#pragma unroll
    for (int i = 0; i < 2; ++i)
#pragma unroll
      for (int rr = 0; rr < 4; ++rr) {
        const float af = __shfl(alpha[i], (lane & 48) | (quad * 4 + rr), 64);
#pragma unroll
        for (int j = 0; j < 8; ++j) oA[i][j][rr] *= af;
      }

    // ---- pack P (keys consecutive in regs) -> 8 b64 LDS writes ----
#pragma unroll
    for (int kk = 0; kk < 4; ++kk)
#pragma unroll
      for (int i = 0; i < 2; ++i) {
        union { float f; unsigned int u; } p0, p1, p2, p3;
        p0.f = sc[kk][i][0]; p1.f = sc[kk][i][1]; p2.f = sc[kk][i][2]; p3.f = sc[kk][i][3];
        uint2 pk;
        pk.x = (p0.u >> 16) | (p1.u & 0xFFFF0000u);
        pk.y = (p2.u >> 16) | (p3.u & 0xFFFF0000u);
        *(uint2*)&sP[(size_t)(wq0 + i * 16 + l15) * 72 + kk * 16 + quad * 4] = pk;
      }

    // ---- O += P V (own sP rows: no barrier; sVt covered by stage barrier) ----
#pragma unroll
    for (int ks = 0; ks < 2; ++ks) {
      bf16x8 pF[2], vF[8];
#pragma unroll
      for (int i = 0; i < 2; ++i)
        pF[i] = *(const bf16x8*)&sP[(size_t)(wq0 + i * 16 + l15) * 72 + ks * 32 + quad * 8];
#pragma unroll
      for (int j = 0; j < 8; ++j) {
        const int n = j * 16 + l15;
        const int blk = (ks * 4 + quad) ^ (l15 & 7);
        vF[j] = *(const bf16x8*)&sVt[(size_t)n * 64 + blk * 8];
      }
#pragma unroll
      for (int i = 0; i < 2; ++i)
#pragma unroll
        for (int j = 0; j < 8; ++j)
          oA[i][j] = mfma16(pF[i], vF[j], oA[i][j]);
    }
  }

  // ---- epilogue: O / l (l fetched to C-layout rows) ----
  float linv[2];
  linv[0] = 1.f / li[0];
  linv[1] = 1.f / li[1];
#pragma unroll
  for (int i = 0; i < 2; ++i)
#pragma unroll
    for (int rr = 0; rr < 4; ++rr) {
      const float lf = __shfl(linv[i], (lane & 48) | (quad * 4 + rr), 64);
      const size_t grow = (size_t)(q0 + wq0 + i * 16 + quad * 4 + rr);
#pragma unroll
      for (int j = 0; j < 8; ++j)
        attnh[grow * 2048 + h * 128 + j * 16 + l15] = f2bf(oA[i][j][rr] * lf);
    }
}

extern "C" void kernel_launch(void* const* d_in, const int* in_sizes, int n_in,
                              void* d_out, int out_size, void* d_ws, size_t ws_size,
                              hipStream_t stream) {
  const float* x        = (const float*)d_in[0];
  const float* wq       = (const float*)d_in[1];
  const float* wkv_a    = (const float*)d_in[2];
  const float* kv_gamma = (const float*)d_in[3];
  const float* kv_beta  = (const float*)d_in[4];
  const float* wkv_b    = (const float*)d_in[5];
  const float* wo       = (const float*)d_in[6];
  float* out = (float*)d_out;

  char* p = (char*)d_ws;
  unsigned short* xh    = (unsigned short*)p; p += (size_t)4096 * 2048 * 2;  // also Vt (aliased after xh dead)
  unsigned short* wqh   = (unsigned short*)p; p += (size_t)3072 * 2048 * 2;
  unsigned short* wah   = (unsigned short*)p; p += (size_t)640 * 2048 * 2;
  unsigned short* wbh   = (unsigned short*)p; p += (size_t)4096 * 512 * 2;
  unsigned short* woh   = (unsigned short*)p; p += (size_t)2048 * 2048 * 2;
  unsigned short* qh    = (unsigned short*)p; p += (size_t)4096 * 3072 * 2;
  float*          kvful = (float*)p;          p += (size_t)4096 * 640 * 4;
  unsigned short* kvlnh = (unsigned short*)p; p += (size_t)4096 * 512 * 2;
  unsigned short* kpeh  = (unsigned short*)p; p += (size_t)4096 * 64 * 2;
  unsigned short* kvbh  = (unsigned short*)p; p += (size_t)4096 * 4096 * 2;
  unsigned short* attnh = (unsigned short*)p; p += (size_t)4096 * 2048 * 2;
  if ((size_t)(p - (char*)d_ws) > ws_size) return;
  unsigned short* Vt = xh;  // 16 MB alias: xh consumed by gemms 1&3 before transpose_v runs

  cast_bf16<<<8192, 256, 0, stream>>>(x,     xh,  4096 * 2048, 4096 * 2048);
  cast_bf16<<<6144, 256, 0, stream>>>(wq,    wqh, 3072 * 2048, 3072 * 2048);
  cast_bf16<<<1280, 256, 0, stream>>>(wkv_a, wah, 576 * 2048,  640 * 2048);
  cast_bf16<<<2048, 256, 0, stream>>>(wkv_b, wbh, 4096 * 512,  4096 * 512);
  cast_bf16<<<4096, 256, 0, stream>>>(wo,    woh, 2048 * 2048, 2048 * 2048);

  // 1. q = QSCALE * (x @ wq^T) -> bf16 (exp2-domain attention)
  gemm_bf16<true><<<dim3(24, 32), 256, 0, stream>>>(xh, wqh, qh, 4096, 3072, 2048, QSCALE);
  // 2. rope(q_pe) in place
  rope_q_bf<<<8192, 256, 0, stream>>>(qh);
  // 3. kv_full = x @ wkv_a^T -> f32 (LN stats precision), padded N=640
  gemm_bf16<false><<<dim3(5, 32), 256, 0, stream>>>(xh, wah, kvful, 4096, 640, 2048, 1.f);
  // 4. layernorm + rope(k_pe) -> bf16
  ln_rope_k<<<4096, 256, 0, stream>>>(kvful, kv_gamma, kv_beta, kvlnh, kpeh);
  // 5. kvb = kvln @ wkv_b^T -> bf16
  gemm_bf16<true><<<dim3(32, 32), 256, 0, stream>>>(kvlnh, wbh, kvbh, 4096, 4096, 512, 1.f);
  // 5b. V^T for attention (overwrites xh — dead by now)
  transpose_v<<<dim3(64, 32), 256, 0, stream>>>(kvbh, Vt);
  // 6. causal MFMA flash attention
  attn_mfma<<<512, 256, 0, stream>>>(qh, kvbh, kpeh, Vt, attnh);
  // 7. out = attn @ wo^T -> f32
  gemm_bf16<false><<<dim3(16, 32), 256, 0, stream>>>(attnh, woh, out, 4096, 2048, 2048, 1.f);
}